// Round 7
// baseline (186.300 us; speedup 1.0000x reference)
//
#include <hip/hip_runtime.h>
#include <hip/hip_bf16.h>
#include <hip/hip_cooperative_groups.h>
#include <stdint.h>

namespace cg = cooperative_groups;

#define Kdim 2048
#define Vdim 768
#define Mdim 4096   // B*N = 16*256

#define BMx 128
#define BNx 128
#define BKx 64
#define NTx (Vdim / BKx)   // 12 K-steps

typedef __attribute__((ext_vector_type(4))) int  i32x4;
typedef __attribute__((ext_vector_type(16))) int i32x16;

#define CFENCE asm volatile("" ::: "memory")

__device__ __forceinline__ void gld_lds16(const void* g, void* l) {
    __builtin_amdgcn_global_load_lds((const __attribute__((address_space(1))) void*)g,
                                     (__attribute__((address_space(3))) void*)l, 16, 0, 0);
}

// ONE cooperative kernel, grid 512 x 256 (all co-resident: 48KB LDS -> 2/CU).
// Phase 1: quantize 6144 rows (3 per wave) -> i8 + scales + sumsq + proto copy.
// grid.sync() (device-scope fences for cross-XCD visibility).
// Phase 2: i8 GEMM, 128x128 tile, BK=64, triple-buffered LDS, counted vmcnt(4),
// XOR-swizzled LDS (both-sides), XCD-swizzled block mapping, fused epilogue.
__global__ __launch_bounds__(256, 2) void fused_dist(const float* __restrict__ x,
                                                     const float* __restrict__ p,
                                                     int8_t* __restrict__ Aq,
                                                     int8_t* __restrict__ Pq,
                                                     float* __restrict__ xsq,
                                                     float* __restrict__ psq,
                                                     float* __restrict__ sxa,
                                                     float* __restrict__ spa,
                                                     float* __restrict__ out) {
    __shared__ int8_t As[3][BMx * BKx];   // 3 x 8KB
    __shared__ int8_t Bs[3][BNx * BKx];   // 3 x 8KB

    const int t = threadIdx.x;
    const int lane = t & 63;
    const int wave = t >> 6;       // 0..3

    // ================= Phase 1: quantization =================
    {
        const int gw = (blockIdx.x << 2) | wave;   // 0..2047
#pragma unroll
        for (int j = 0; j < 3; ++j) {
            const int row = gw + j * 2048;         // 0..6143
            const float* src;
            int8_t* dq;
            float *sq, *sc, *cpy = nullptr;
            if (row < Mdim) {
                src = x + (size_t)row * Vdim; dq = Aq + (size_t)row * Vdim;
                sq = xsq + row; sc = sxa + row;
            } else {
                const int r = row - Mdim;
                src = p + (size_t)r * Vdim; dq = Pq + (size_t)r * Vdim;
                sq = psq + r; sc = spa + r;
                cpy = out + (size_t)Mdim * Kdim + (size_t)r * Vdim;
            }

            float4 v[3];
            float s = 0.f, mx = 0.f;
#pragma unroll
            for (int c = 0; c < 3; ++c) {
                v[c] = *reinterpret_cast<const float4*>(src + c * 256 + lane * 4);
                s += v[c].x * v[c].x + v[c].y * v[c].y + v[c].z * v[c].z + v[c].w * v[c].w;
                mx = fmaxf(mx, fmaxf(fmaxf(fabsf(v[c].x), fabsf(v[c].y)),
                                     fmaxf(fabsf(v[c].z), fabsf(v[c].w))));
                if (cpy) *reinterpret_cast<float4*>(cpy + c * 256 + lane * 4) = v[c];
            }
#pragma unroll
            for (int off = 32; off > 0; off >>= 1) {
                s += __shfl_xor(s, off);
                mx = fmaxf(mx, __shfl_xor(mx, off));
            }
            mx = fmaxf(mx, 1e-20f);
            const float inv = 127.0f / mx;
#pragma unroll
            for (int c = 0; c < 3; ++c) {
                int q0 = min(127, max(-127, __float2int_rn(v[c].x * inv)));
                int q1 = min(127, max(-127, __float2int_rn(v[c].y * inv)));
                int q2 = min(127, max(-127, __float2int_rn(v[c].z * inv)));
                int q3 = min(127, max(-127, __float2int_rn(v[c].w * inv)));
                int packed = (q0 & 0xff) | ((q1 & 0xff) << 8) | ((q2 & 0xff) << 16) | (q3 << 24);
                *reinterpret_cast<int*>(dq + c * 256 + lane * 4) = packed;
            }
            if (lane == 0) { *sq = s; *sc = mx * (1.0f / 127.0f); }
        }
    }

    // Device-scope release (cross-XCD L2 writeback), grid barrier, acquire.
    __threadfence();
    cg::this_grid().sync();
    __threadfence();

    // ================= Phase 2: GEMM =================
    const int wr = wave >> 1;      // 0..1 (M)
    const int wc = wave & 1;       // 0..1 (N)
    const int ln31 = lane & 31;
    const int lh = lane >> 5;      // 0..1

    // T1: bijective XCD swizzle (512 blocks % 8 == 0)
    const int wg = (blockIdx.x & 7) * 64 + (blockIdx.x >> 3);
    const int bm = wg >> 4;        // 0..31
    const int bn = wg & 15;        // 0..15
    const int m0 = bm * BMx, n0 = bn * BNx;

    // Staging: linear LDS dest (gld_lds writes base + lane*16), inverse-swizzled
    // global source. One block-wide issue = 4KB = 64 rows x 64B; thread t ->
    // row t>>2, phys 16B-slot t&3, sourcing logical slot (t&3) ^ ((row>>1)&3).
    const int srow = t >> 2;                               // 0..63
    const int scol = ((t & 3) ^ ((srow >> 1) & 3)) * 16;   // i8 elements
    const int8_t* Ag = Aq + (size_t)(m0 + srow) * Vdim + scol;
    const int8_t* Bg = Pq + (size_t)(n0 + srow) * Vdim + scol;
    const int ldsoff = wave * 1024;                        // wave slice of a 4KB issue

    // Swizzled ds_read byte offsets: row r, logical 16B-slot S -> phys S^((r>>1)&3).
    int offA[2][2], offB[2][2];
#pragma unroll
    for (int mt = 0; mt < 2; ++mt)
#pragma unroll
        for (int ks = 0; ks < 2; ++ks) {
            const int S = ks * 2 + lh;
            const int rA = wr * 64 + mt * 32 + ln31;
            const int rB = wc * 64 + mt * 32 + ln31;
            offA[mt][ks] = rA * BKx + ((S ^ ((rA >> 1) & 3)) * 16);
            offB[mt][ks] = rB * BKx + ((S ^ ((rB >> 1) & 3)) * 16);
        }

    auto stage = [&](int buf, int kt) {
#pragma unroll
        for (int q = 0; q < 2; ++q)
            gld_lds16(Ag + (size_t)q * 64 * Vdim + kt * BKx, (void*)(&As[buf][q * 4096 + ldsoff]));
#pragma unroll
        for (int q = 0; q < 2; ++q)
            gld_lds16(Bg + (size_t)q * 64 * Vdim + kt * BKx, (void*)(&Bs[buf][q * 4096 + ldsoff]));
    };

    i32x16 acc[2][2] = {};

    // Prologue: stage K-steps 0,1,2 (12 instrs/wave); wait step 0 (8 in flight).
    stage(0, 0); stage(1, 1); stage(2, 2);
    asm volatile("s_waitcnt vmcnt(8)" ::: "memory");
    __builtin_amdgcn_s_barrier();
    CFENCE;

    int cb = 0, cs = 0;
    for (int kt = 0; kt < NTx; ++kt) {
        if (kt + 2 < NTx) {
            cs = cb + 2; if (cs >= 3) cs -= 3;
            stage(cs, kt + 2);             // issue prefetch FIRST
        }

        const int8_t* Ap = &As[cb][0];
        const int8_t* Bp = &Bs[cb][0];
        i32x4 af[2][2], bf[2][2];
#pragma unroll
        for (int mt = 0; mt < 2; ++mt)
#pragma unroll
            for (int ks = 0; ks < 2; ++ks) {
                af[mt][ks] = *reinterpret_cast<const i32x4*>(Ap + offA[mt][ks]);
                bf[mt][ks] = *reinterpret_cast<const i32x4*>(Bp + offB[mt][ks]);
            }
        CFENCE;
        __builtin_amdgcn_s_setprio(1);
#pragma unroll
        for (int ks = 0; ks < 2; ++ks)
#pragma unroll
            for (int mt = 0; mt < 2; ++mt)
#pragma unroll
                for (int nt = 0; nt < 2; ++nt)
                    acc[mt][nt] = __builtin_amdgcn_mfma_i32_32x32x32_i8(af[mt][ks], bf[nt][ks], acc[mt][nt], 0, 0, 0);
        __builtin_amdgcn_s_setprio(0);
        CFENCE;
        // Counted wait: K-step kt+1 landed; kt+2's 4 issues stay in flight.
        if (kt + 2 < NTx)       asm volatile("s_waitcnt vmcnt(4)" ::: "memory");
        else if (kt + 2 == NTx) asm volatile("s_waitcnt vmcnt(0)" ::: "memory");
        if (kt + 1 < NTx) { __builtin_amdgcn_s_barrier(); CFENCE; }
        cb = cb + 1; if (cb >= 3) cb -= 3;
    }

    // Epilogue. 32x32 C/D layout: col=lane&31, row=(reg&3)+8*(reg>>2)+4*(lane>>5).
    float ps_[2], sp_[2];
    int col_[2];
#pragma unroll
    for (int nt = 0; nt < 2; ++nt) {
        col_[nt] = n0 + wc * 64 + nt * 32 + ln31;
        ps_[nt] = psq[col_[nt]];
        sp_[nt] = spa[col_[nt]];
    }
#pragma unroll
    for (int mt = 0; mt < 2; ++mt)
#pragma unroll
        for (int reg = 0; reg < 16; ++reg) {
            const int row = m0 + wr * 64 + mt * 32 + (reg & 3) + 8 * (reg >> 2) + 4 * lh;
            const float xs = xsq[row];
            const float m2sx = -2.0f * sxa[row];
#pragma unroll
            for (int nt = 0; nt < 2; ++nt)
                out[(size_t)row * Kdim + col_[nt]] =
                    xs + ps_[nt] + m2sx * sp_[nt] * (float)acc[mt][nt][reg];
        }
}

extern "C" void kernel_launch(void* const* d_in, const int* in_sizes, int n_in,
                              void* d_out, int out_size, void* d_ws, size_t ws_size,
                              hipStream_t stream) {
    const float* x = (const float*)d_in[0];   // (16,256,768) fp32
    const float* p = (const float*)d_in[1];   // (2048,768) fp32
    float* out = (float*)d_out;               // distances (4096x2048) + prototypes (2048x768)

    char* ws = (char*)d_ws;
    int8_t* Aq = (int8_t*)ws;                          // 3,145,728 B
    int8_t* Pq = (int8_t*)(ws + 3145728);              // 1,572,864 B
    float* xsq = (float*)(ws + 4718592);               // 16,384 B
    float* psq = (float*)(ws + 4734976);               // 8,192 B
    float* sxa = (float*)(ws + 4743168);               // 16,384 B
    float* spa = (float*)(ws + 4759552);               // 8,192 B

    void* args[] = {(void*)&x, (void*)&p, (void*)&Aq, (void*)&Pq, (void*)&xsq,
                    (void*)&psq, (void*)&sxa, (void*)&spa, (void*)&out};
    hipLaunchCooperativeKernel((void*)fused_dist, dim3((Mdim / BMx) * (Kdim / BNx)),
                               dim3(256), args, 0, stream);
}

// Round 8
// 75.099 us; speedup vs baseline: 2.4807x; 2.4807x over previous
//
#include <hip/hip_runtime.h>
#include <hip/hip_bf16.h>
#include <stdint.h>

#define Kdim 2048
#define Vdim 768
#define Mdim 4096   // B*N = 16*256

#define BMx 128
#define BNx 128
#define BKx 64
#define NTx (Vdim / BKx)   // 12 K-steps
#define NBLK 512

typedef __attribute__((ext_vector_type(4))) int  i32x4;
typedef __attribute__((ext_vector_type(16))) int i32x16;

#define CFENCE asm volatile("" ::: "memory")

__device__ __forceinline__ void gld_lds16(const void* g, void* l) {
    __builtin_amdgcn_global_load_lds((const __attribute__((address_space(1))) void*)g,
                                     (__attribute__((address_space(3))) void*)l, 16, 0, 0);
}

// ONE normal kernel, grid 512 x 256. 48KB LDS + launch_bounds(256,2) ->
// 2 blocks/CU guaranteed -> all 512 blocks co-resident (cap = 512).
// Phase 1: quantize (XCD-aligned A rows: block b owns rows the GEMM blocks of
//          its XCD will read) + P rows + proto fp32 pass-through.
// Hand-rolled grid barrier: agent-scope atomics + s_sleep spin (cg::grid.sync
// measured ~150us in R7; this is the lean version).
// Phase 2: R6's i8 GEMM verbatim (triple-buffer, counted vmcnt(4), XOR swizzle,
//          XCD-swizzled tiles, fused distance epilogue).
__global__ __launch_bounds__(256, 2) void fused_dist(const float* __restrict__ x,
                                                     const float* __restrict__ p,
                                                     int8_t* __restrict__ Aq,
                                                     int8_t* __restrict__ Pq,
                                                     float* __restrict__ xsq,
                                                     float* __restrict__ psq,
                                                     float* __restrict__ sxa,
                                                     float* __restrict__ spa,
                                                     unsigned int* __restrict__ cnt,
                                                     float* __restrict__ out) {
    __shared__ int8_t As[3][BMx * BKx];   // 3 x 8KB
    __shared__ int8_t Bs[3][BNx * BKx];   // 3 x 8KB

    const int t = threadIdx.x;
    const int lane = t & 63;
    const int wave = t >> 6;       // 0..3
    const int xcd = blockIdx.x & 7;
    const int seq = blockIdx.x >> 3;

    // ================= Phase 1: quantization =================
    {
        auto dorow = [&](const float* src, int8_t* dq, float* sq, float* sc, float* cpy) {
            float4 v[3];
            float s = 0.f, mx = 0.f;
#pragma unroll
            for (int c = 0; c < 3; ++c) {
                v[c] = *reinterpret_cast<const float4*>(src + c * 256 + lane * 4);
                s += v[c].x * v[c].x + v[c].y * v[c].y + v[c].z * v[c].z + v[c].w * v[c].w;
                mx = fmaxf(mx, fmaxf(fmaxf(fabsf(v[c].x), fabsf(v[c].y)),
                                     fmaxf(fabsf(v[c].z), fabsf(v[c].w))));
                if (cpy) *reinterpret_cast<float4*>(cpy + c * 256 + lane * 4) = v[c];
            }
#pragma unroll
            for (int off = 32; off > 0; off >>= 1) {
                s += __shfl_xor(s, off);
                mx = fmaxf(mx, __shfl_xor(mx, off));
            }
            mx = fmaxf(mx, 1e-20f);
            const float inv = 127.0f / mx;
#pragma unroll
            for (int c = 0; c < 3; ++c) {
                int q0 = min(127, max(-127, __float2int_rn(v[c].x * inv)));
                int q1 = min(127, max(-127, __float2int_rn(v[c].y * inv)));
                int q2 = min(127, max(-127, __float2int_rn(v[c].z * inv)));
                int q3 = min(127, max(-127, __float2int_rn(v[c].w * inv)));
                int packed = (q0 & 0xff) | ((q1 & 0xff) << 8) | ((q2 & 0xff) << 16) | (q3 << 24);
                *reinterpret_cast<int*>(dq + c * 256 + lane * 4) = packed;
            }
            if (lane == 0) { *sq = s; *sc = mx * (1.0f / 127.0f); }
        };

        // A rows: XCD-aligned — block b handles 8 rows of the 512-row panel
        // its XCD's GEMM tiles consume (XCD x owns bm in [4x,4x+4)).
        const int ar = xcd * 512 + seq * 8 + wave * 2;
        dorow(x + (size_t)ar * Vdim, Aq + (size_t)ar * Vdim, xsq + ar, sxa + ar, nullptr);
        dorow(x + (size_t)(ar + 1) * Vdim, Aq + (size_t)(ar + 1) * Vdim,
              xsq + ar + 1, sxa + ar + 1, nullptr);
        // P rows: 4 per block, incl. fp32 pass-through to out tail.
        const int pr = blockIdx.x * 4 + wave;
        dorow(p + (size_t)pr * Vdim, Pq + (size_t)pr * Vdim, psq + pr, spa + pr,
              out + (size_t)Mdim * Kdim + (size_t)pr * Vdim);
    }

    // ================= Grid barrier (lean, agent-scope) =================
    __syncthreads();   // drains all waves' vmem (s_waitcnt vmcnt(0) before s_barrier)
    if (t == 0) {
        __hip_atomic_fetch_add(cnt, 1u, __ATOMIC_RELEASE, __HIP_MEMORY_SCOPE_AGENT);
        unsigned int v;
        do {
            v = __hip_atomic_load(cnt, __ATOMIC_ACQUIRE, __HIP_MEMORY_SCOPE_AGENT);
            if (v < NBLK) __builtin_amdgcn_s_sleep(2);
        } while (v < NBLK);
    }
    __syncthreads();

    // ================= Phase 2: GEMM =================
    const int wr = wave >> 1;      // 0..1 (M)
    const int wc = wave & 1;       // 0..1 (N)
    const int ln31 = lane & 31;
    const int lh = lane >> 5;      // 0..1

    // T1: bijective XCD swizzle (512 blocks % 8 == 0)
    const int wg = xcd * 64 + seq;
    const int bm = wg >> 4;        // 0..31
    const int bn = wg & 15;        // 0..15
    const int m0 = bm * BMx, n0 = bn * BNx;

    // Staging: linear LDS dest, inverse-swizzled global source. One block-wide
    // issue = 4KB = 64 rows x 64B; thread t -> row t>>2, phys 16B-slot t&3,
    // sourcing logical slot (t&3) ^ ((row>>1)&3).
    const int srow = t >> 2;                               // 0..63
    const int scol = ((t & 3) ^ ((srow >> 1) & 3)) * 16;   // i8 elements
    const int8_t* Ag = Aq + (size_t)(m0 + srow) * Vdim + scol;
    const int8_t* Bg = Pq + (size_t)(n0 + srow) * Vdim + scol;
    const int ldsoff = wave * 1024;                        // wave slice of a 4KB issue

    // Swizzled ds_read byte offsets: row r, logical 16B-slot S -> phys S^((r>>1)&3).
    int offA[2][2], offB[2][2];
#pragma unroll
    for (int mt = 0; mt < 2; ++mt)
#pragma unroll
        for (int ks = 0; ks < 2; ++ks) {
            const int S = ks * 2 + lh;
            const int rA = wr * 64 + mt * 32 + ln31;
            const int rB = wc * 64 + mt * 32 + ln31;
            offA[mt][ks] = rA * BKx + ((S ^ ((rA >> 1) & 3)) * 16);
            offB[mt][ks] = rB * BKx + ((S ^ ((rB >> 1) & 3)) * 16);
        }

    auto stage = [&](int buf, int kt) {
#pragma unroll
        for (int q = 0; q < 2; ++q)
            gld_lds16(Ag + (size_t)q * 64 * Vdim + kt * BKx, (void*)(&As[buf][q * 4096 + ldsoff]));
#pragma unroll
        for (int q = 0; q < 2; ++q)
            gld_lds16(Bg + (size_t)q * 64 * Vdim + kt * BKx, (void*)(&Bs[buf][q * 4096 + ldsoff]));
    };

    i32x16 acc[2][2] = {};

    // Prologue: stage K-steps 0,1,2 (12 instrs/wave); wait step 0 (8 in flight).
    stage(0, 0); stage(1, 1); stage(2, 2);
    asm volatile("s_waitcnt vmcnt(8)" ::: "memory");
    __builtin_amdgcn_s_barrier();
    CFENCE;

    int cb = 0, cs = 0;
    for (int kt = 0; kt < NTx; ++kt) {
        if (kt + 2 < NTx) {
            cs = cb + 2; if (cs >= 3) cs -= 3;
            stage(cs, kt + 2);             // issue prefetch FIRST
        }

        const int8_t* Ap = &As[cb][0];
        const int8_t* Bp = &Bs[cb][0];
        i32x4 af[2][2], bf[2][2];
#pragma unroll
        for (int mt = 0; mt < 2; ++mt)
#pragma unroll
            for (int ks = 0; ks < 2; ++ks) {
                af[mt][ks] = *reinterpret_cast<const i32x4*>(Ap + offA[mt][ks]);
                bf[mt][ks] = *reinterpret_cast<const i32x4*>(Bp + offB[mt][ks]);
            }
        CFENCE;
        __builtin_amdgcn_s_setprio(1);
#pragma unroll
        for (int ks = 0; ks < 2; ++ks)
#pragma unroll
            for (int mt = 0; mt < 2; ++mt)
#pragma unroll
                for (int nt = 0; nt < 2; ++nt)
                    acc[mt][nt] = __builtin_amdgcn_mfma_i32_32x32x32_i8(af[mt][ks], bf[nt][ks], acc[mt][nt], 0, 0, 0);
        __builtin_amdgcn_s_setprio(0);
        CFENCE;
        // Counted wait: K-step kt+1 landed; kt+2's 4 issues stay in flight.
        if (kt + 2 < NTx)       asm volatile("s_waitcnt vmcnt(4)" ::: "memory");
        else if (kt + 2 == NTx) asm volatile("s_waitcnt vmcnt(0)" ::: "memory");
        if (kt + 1 < NTx) { __builtin_amdgcn_s_barrier(); CFENCE; }
        cb = cb + 1; if (cb >= 3) cb -= 3;
    }

    // Epilogue. 32x32 C/D layout: col=lane&31, row=(reg&3)+8*(reg>>2)+4*(lane>>5).
    float ps_[2], sp_[2];
    int col_[2];
#pragma unroll
    for (int nt = 0; nt < 2; ++nt) {
        col_[nt] = n0 + wc * 64 + nt * 32 + ln31;
        ps_[nt] = psq[col_[nt]];
        sp_[nt] = spa[col_[nt]];
    }
#pragma unroll
    for (int mt = 0; mt < 2; ++mt)
#pragma unroll
        for (int reg = 0; reg < 16; ++reg) {
            const int row = m0 + wr * 64 + mt * 32 + (reg & 3) + 8 * (reg >> 2) + 4 * lh;
            const float xs = xsq[row];
            const float m2sx = -2.0f * sxa[row];
#pragma unroll
            for (int nt = 0; nt < 2; ++nt)
                out[(size_t)row * Kdim + col_[nt]] =
                    xs + ps_[nt] + m2sx * sp_[nt] * (float)acc[mt][nt][reg];
        }
}

extern "C" void kernel_launch(void* const* d_in, const int* in_sizes, int n_in,
                              void* d_out, int out_size, void* d_ws, size_t ws_size,
                              hipStream_t stream) {
    const float* x = (const float*)d_in[0];   // (16,256,768) fp32
    const float* p = (const float*)d_in[1];   // (2048,768) fp32
    float* out = (float*)d_out;               // distances (4096x2048) + prototypes (2048x768)

    char* ws = (char*)d_ws;
    int8_t* Aq = (int8_t*)ws;                          // 3,145,728 B
    int8_t* Pq = (int8_t*)(ws + 3145728);              // 1,572,864 B
    float* xsq = (float*)(ws + 4718592);               // 16,384 B
    float* psq = (float*)(ws + 4734976);               // 8,192 B
    float* sxa = (float*)(ws + 4743168);               // 16,384 B
    float* spa = (float*)(ws + 4759552);               // 8,192 B
    unsigned int* cnt = (unsigned int*)(ws + 4767744); // 4 B barrier counter

    hipMemsetAsync((void*)cnt, 0, 4, stream);          // deterministic across replays
    fused_dist<<<NBLK, 256, 0, stream>>>(x, p, Aq, Pq, xsq, psq, sxa, spa, cnt, out);
}

// Round 9
// 27.922 us; speedup vs baseline: 6.6720x; 2.6895x over previous
//
#include <hip/hip_runtime.h>
#include <hip/hip_bf16.h>
#include <stdint.h>

#define Kdim 2048
#define Vdim 768
#define Mdim 4096   // B*N = 16*256

#define BMx 128
#define BNx 128
#define BKx 64
#define NTx (Vdim / BKx)   // 12 K-steps
#define PIPE 4             // LDS pipeline depth (stage 3 ahead)

typedef __attribute__((ext_vector_type(4))) int  i32x4;
typedef __attribute__((ext_vector_type(16))) int i32x16;

#define CFENCE asm volatile("" ::: "memory")

__device__ __forceinline__ void gld_lds16(const void* g, void* l) {
    __builtin_amdgcn_global_load_lds((const __attribute__((address_space(1))) void*)g,
                                     (__attribute__((address_space(3))) void*)l, 16, 0, 0);
}

// One wave per row. A-rows are XCD-ALIGNED to the GEMM's consumer XCD:
// GEMM block with (blockIdx&7)==x reads A rows [x*512, x*512+512), so
// rowquant block b (A-part) produces rows (b&7)*512 + (b>>3)*4 + wave ->
// Aq lines are dirty in the consumer XCD's L2 across the kernel boundary.
__global__ __launch_bounds__(256) void rowquant(const float* __restrict__ x,
                                                const float* __restrict__ p,
                                                int8_t* __restrict__ Aq,
                                                int8_t* __restrict__ Pq,
                                                float* __restrict__ xsq,
                                                float* __restrict__ psq,
                                                float* __restrict__ sxa,
                                                float* __restrict__ spa,
                                                float* __restrict__ proto_out) {
    const int b = blockIdx.x;
    const int wave = threadIdx.x >> 6;
    const int lane = threadIdx.x & 63;

    const float* src;
    int8_t* dq;
    float *sq, *sc, *cpy = nullptr;
    if (b < 1024) {   // A rows, XCD-aligned
        const int row = (b & 7) * 512 + (b >> 3) * 4 + wave;
        src = x + (size_t)row * Vdim; dq = Aq + (size_t)row * Vdim;
        sq = xsq + row; sc = sxa + row;
    } else {          // P rows + fp32 pass-through
        const int r = (b - 1024) * 4 + wave;
        src = p + (size_t)r * Vdim; dq = Pq + (size_t)r * Vdim;
        sq = psq + r; sc = spa + r;
        cpy = proto_out + (size_t)r * Vdim;
    }

    float4 v[3];
    float s = 0.f, mx = 0.f;
#pragma unroll
    for (int c = 0; c < 3; ++c) {
        v[c] = *reinterpret_cast<const float4*>(src + c * 256 + lane * 4);
        s += v[c].x * v[c].x + v[c].y * v[c].y + v[c].z * v[c].z + v[c].w * v[c].w;
        mx = fmaxf(mx, fmaxf(fmaxf(fabsf(v[c].x), fabsf(v[c].y)),
                             fmaxf(fabsf(v[c].z), fabsf(v[c].w))));
        if (cpy) *reinterpret_cast<float4*>(cpy + c * 256 + lane * 4) = v[c];
    }
#pragma unroll
    for (int off = 32; off > 0; off >>= 1) {
        s += __shfl_xor(s, off);
        mx = fmaxf(mx, __shfl_xor(mx, off));
    }
    mx = fmaxf(mx, 1e-20f);
    const float inv = 127.0f / mx;
#pragma unroll
    for (int c = 0; c < 3; ++c) {
        int q0 = min(127, max(-127, __float2int_rn(v[c].x * inv)));
        int q1 = min(127, max(-127, __float2int_rn(v[c].y * inv)));
        int q2 = min(127, max(-127, __float2int_rn(v[c].z * inv)));
        int q3 = min(127, max(-127, __float2int_rn(v[c].w * inv)));
        int packed = (q0 & 0xff) | ((q1 & 0xff) << 8) | ((q2 & 0xff) << 16) | (q3 << 24);
        *reinterpret_cast<int*>(dq + c * 256 + lane * 4) = packed;
    }
    if (lane == 0) { *sq = s; *sc = mx * (1.0f / 127.0f); }
}

// i8 GEMM: 128x128 tile, BK=64, 4 waves (2x2, 64x64/wave), PIPE=4 LDS
// pipeline (64KB -> 2 blocks/CU), stage 3 K-steps ahead, steady vmcnt(8)
// (issue-to-wait distance ~3 K-steps, covers L3/HBM latency), XOR-swizzled
// LDS both-sides, XCD-swizzled grid, fused distance epilogue.
__global__ __launch_bounds__(256, 2) void gemm_dist_i8(const int8_t* __restrict__ Aq,
                                                       const int8_t* __restrict__ Pq,
                                                       const float* __restrict__ xsq,
                                                       const float* __restrict__ psq,
                                                       const float* __restrict__ sxa,
                                                       const float* __restrict__ spa,
                                                       float* __restrict__ out) {
    __shared__ int8_t As[PIPE][BMx * BKx];   // 4 x 8KB
    __shared__ int8_t Bs[PIPE][BNx * BKx];   // 4 x 8KB

    const int t = threadIdx.x;
    const int lane = t & 63;
    const int wave = t >> 6;       // 0..3
    const int wr = wave >> 1;      // 0..1 (M)
    const int wc = wave & 1;       // 0..1 (N)
    const int ln31 = lane & 31;
    const int lh = lane >> 5;      // 0..1

    // T1: bijective XCD swizzle (512 blocks % 8 == 0); XCD x -> bm in [4x,4x+4)
    const int wg = (blockIdx.x & 7) * 64 + (blockIdx.x >> 3);
    const int bm = wg >> 4;        // 0..31
    const int bn = wg & 15;        // 0..15
    const int m0 = bm * BMx, n0 = bn * BNx;

    // Staging: linear LDS dest, inverse-swizzled global source. One block-wide
    // issue = 4KB = 64 rows x 64B; thread t -> row t>>2, phys 16B-slot t&3,
    // sourcing logical slot (t&3) ^ ((row>>1)&3).
    const int srow = t >> 2;                               // 0..63
    const int scol = ((t & 3) ^ ((srow >> 1) & 3)) * 16;   // i8 elements
    const int8_t* Ag = Aq + (size_t)(m0 + srow) * Vdim + scol;
    const int8_t* Bg = Pq + (size_t)(n0 + srow) * Vdim + scol;
    const int ldsoff = wave * 1024;                        // wave slice of a 4KB issue

    // Swizzled ds_read byte offsets: row r, logical 16B-slot S -> phys S^((r>>1)&3).
    int offA[2][2], offB[2][2];
#pragma unroll
    for (int mt = 0; mt < 2; ++mt)
#pragma unroll
        for (int ks = 0; ks < 2; ++ks) {
            const int S = ks * 2 + lh;
            const int rA = wr * 64 + mt * 32 + ln31;
            const int rB = wc * 64 + mt * 32 + ln31;
            offA[mt][ks] = rA * BKx + ((S ^ ((rA >> 1) & 3)) * 16);
            offB[mt][ks] = rB * BKx + ((S ^ ((rB >> 1) & 3)) * 16);
        }

    auto stage = [&](int buf, int kt) {
#pragma unroll
        for (int q = 0; q < 2; ++q)
            gld_lds16(Ag + (size_t)q * 64 * Vdim + kt * BKx, (void*)(&As[buf][q * 4096 + ldsoff]));
#pragma unroll
        for (int q = 0; q < 2; ++q)
            gld_lds16(Bg + (size_t)q * 64 * Vdim + kt * BKx, (void*)(&Bs[buf][q * 4096 + ldsoff]));
    };

    i32x16 acc[2][2] = {};

    // Prologue: stage K-steps 0,1,2 (12 instrs/wave); wait step 0 (8 in flight).
    stage(0, 0); stage(1, 1); stage(2, 2);
    asm volatile("s_waitcnt vmcnt(8)" ::: "memory");
    __builtin_amdgcn_s_barrier();
    CFENCE;

    for (int kt = 0; kt < NTx; ++kt) {
        const int cb = kt & 3;
        if (kt + 3 < NTx) stage((kt + 3) & 3, kt + 3);   // 3-ahead prefetch

        const int8_t* Ap = &As[cb][0];
        const int8_t* Bp = &Bs[cb][0];
        i32x4 af[2][2], bf[2][2];
#pragma unroll
        for (int mt = 0; mt < 2; ++mt)
#pragma unroll
            for (int ks = 0; ks < 2; ++ks) {
                af[mt][ks] = *reinterpret_cast<const i32x4*>(Ap + offA[mt][ks]);
                bf[mt][ks] = *reinterpret_cast<const i32x4*>(Bp + offB[mt][ks]);
            }
        CFENCE;
        __builtin_amdgcn_s_setprio(1);
#pragma unroll
        for (int ks = 0; ks < 2; ++ks)
#pragma unroll
            for (int mt = 0; mt < 2; ++mt)
#pragma unroll
                for (int nt = 0; nt < 2; ++nt)
                    acc[mt][nt] = __builtin_amdgcn_mfma_i32_32x32x32_i8(af[mt][ks], bf[nt][ks], acc[mt][nt], 0, 0, 0);
        __builtin_amdgcn_s_setprio(0);
        CFENCE;
        // Counted wait: K-step kt+1 must have landed; up to 2 more tiles in flight.
        if (kt <= NTx - 4)      asm volatile("s_waitcnt vmcnt(8)" ::: "memory");
        else if (kt == NTx - 3) asm volatile("s_waitcnt vmcnt(4)" ::: "memory");
        else if (kt == NTx - 2) asm volatile("s_waitcnt vmcnt(0)" ::: "memory");
        if (kt + 1 < NTx) { __builtin_amdgcn_s_barrier(); CFENCE; }
    }

    // Epilogue. 32x32 C/D layout: col=lane&31, row=(reg&3)+8*(reg>>2)+4*(lane>>5).
    float ps_[2], sp_[2];
    int col_[2];
#pragma unroll
    for (int nt = 0; nt < 2; ++nt) {
        col_[nt] = n0 + wc * 64 + nt * 32 + ln31;
        ps_[nt] = psq[col_[nt]];
        sp_[nt] = spa[col_[nt]];
    }
#pragma unroll
    for (int mt = 0; mt < 2; ++mt)
#pragma unroll
        for (int reg = 0; reg < 16; ++reg) {
            const int row = m0 + wr * 64 + mt * 32 + (reg & 3) + 8 * (reg >> 2) + 4 * lh;
            const float xs = xsq[row];
            const float m2sx = -2.0f * sxa[row];
#pragma unroll
            for (int nt = 0; nt < 2; ++nt)
                out[(size_t)row * Kdim + col_[nt]] =
                    xs + ps_[nt] + m2sx * sp_[nt] * (float)acc[mt][nt][reg];
        }
}

extern "C" void kernel_launch(void* const* d_in, const int* in_sizes, int n_in,
                              void* d_out, int out_size, void* d_ws, size_t ws_size,
                              hipStream_t stream) {
    const float* x = (const float*)d_in[0];   // (16,256,768) fp32
    const float* p = (const float*)d_in[1];   // (2048,768) fp32
    float* out = (float*)d_out;               // distances (4096x2048) + prototypes (2048x768)

    char* ws = (char*)d_ws;
    int8_t* Aq = (int8_t*)ws;                          // 3,145,728 B
    int8_t* Pq = (int8_t*)(ws + 3145728);              // 1,572,864 B
    float* xsq = (float*)(ws + 4718592);               // 16,384 B
    float* psq = (float*)(ws + 4734976);               // 8,192 B
    float* sxa = (float*)(ws + 4743168);               // 16,384 B
    float* spa = (float*)(ws + 4759552);               // 8,192 B

    rowquant<<<(Mdim + Kdim) / 4, 256, 0, stream>>>(x, p, Aq, Pq, xsq, psq, sxa, spa,
                                                    out + (size_t)Mdim * Kdim);
    gemm_dist_i8<<<(Mdim / BMx) * (Kdim / BNx), 256, 0, stream>>>(Aq, Pq, xsq, psq, sxa, spa, out);
}